// Round 1
// baseline (563.129 us; speedup 1.0000x reference)
//
#include <hip/hip_runtime.h>

#define N_NODES 10000
#define EDGES   160000
#define BATCH   8
#define TT      12
#define HID     64

// ---------------- CSR build ----------------

__global__ __launch_bounds__(256) void k_deg_hist(const int* __restrict__ ei,
                                                  const float* __restrict__ ew,
                                                  float* __restrict__ deg,
                                                  int* __restrict__ cnt) {
  int g = blockIdx.x * 256 + threadIdx.x;
  if (g < EDGES) {
    int d = ei[EDGES + g];
    atomicAdd(&deg[d], ew[g]);
    atomicAdd(&cnt[d], 1);
  }
}

__global__ __launch_bounds__(256) void k_dinv(const float* __restrict__ deg,
                                              float* __restrict__ dinv) {
  int g = blockIdx.x * 256 + threadIdx.x;
  if (g < N_NODES) dinv[g] = 1.0f / sqrtf(deg[g] + 1.0f);  // +1 = self-loop weight
}

__global__ __launch_bounds__(1024) void k_scan(const int* __restrict__ cnt,
                                               int* __restrict__ row_ptr,
                                               int* __restrict__ cursor) {
  __shared__ int part[1024];
  int tid = threadIdx.x;
  int base = tid * 10;
  int local[10];
  int s = 0;
  #pragma unroll
  for (int j = 0; j < 10; j++) {
    int idx = base + j;
    int v = (idx < N_NODES) ? cnt[idx] : 0;
    local[j] = s;
    s += v;
  }
  part[tid] = s;
  __syncthreads();
  for (int off = 1; off < 1024; off <<= 1) {
    int v = (tid >= off) ? part[tid - off] : 0;
    __syncthreads();
    part[tid] += v;
    __syncthreads();
  }
  int pre = (tid > 0) ? part[tid - 1] : 0;
  #pragma unroll
  for (int j = 0; j < 10; j++) {
    int idx = base + j;
    if (idx < N_NODES) {
      int rpv = pre + local[j];
      row_ptr[idx] = rpv;
      cursor[idx]  = rpv;
    }
  }
  if (tid == 0) row_ptr[N_NODES] = part[1023];
}

__global__ __launch_bounds__(256) void k_fill(const int* __restrict__ ei,
                                              const float* __restrict__ ew,
                                              const float* __restrict__ dinv,
                                              int* __restrict__ cursor,
                                              int* __restrict__ csrc,
                                              float* __restrict__ cnorm) {
  int g = blockIdx.x * 256 + threadIdx.x;
  if (g < EDGES) {
    int s = ei[g], d = ei[EDGES + g];
    int slot = atomicAdd(&cursor[d], 1);
    csrc[slot]  = s;
    cnorm[slot] = dinv[s] * ew[g] * dinv[d];
  }
}

// pack tc?_w (O=64, I=64, K=3) -> [k][i][o] row-major (192 x 64)
__global__ __launch_bounds__(256) void k_pack(const float* __restrict__ w1,
                                              const float* __restrict__ w2,
                                              float* __restrict__ p1,
                                              float* __restrict__ p2) {
  int g = blockIdx.x * 256 + threadIdx.x;  // 0..24575
  int sel = g / 12288, r = g % 12288;
  int o = r & 63, ki = r >> 6;
  int i = ki & 63, k = ki >> 6;
  const float* src = sel ? w2 : w1;
  float* dst = sel ? p2 : p1;
  dst[r] = src[o * 192 + i * 3 + k];
}

// ---------------- GCN ----------------

// aggregate raw X (2 features) for one timestep: ax[b,n,:] = dinv[n]^2*x[b,n,:] + sum_e norm*x[b,src,:]
__global__ __launch_bounds__(256) void k_agg2(const float* __restrict__ X, int t,
                                              const float* __restrict__ dinv,
                                              const int* __restrict__ rp,
                                              const int* __restrict__ csrc,
                                              const float* __restrict__ cnorm,
                                              float* __restrict__ ax) {
  int g = blockIdx.x * 256 + threadIdx.x;
  if (g >= BATCH * N_NODES) return;
  int n = g % N_NODES, b = g / N_NODES;
  const float2* xb = (const float2*)(X + (size_t)(b * TT + t) * N_NODES * 2);
  float di = dinv[n];
  float2 xv = xb[n];
  float a0 = di * di * xv.x, a1 = di * di * xv.y;
  int e1 = rp[n + 1];
  for (int e = rp[n]; e < e1; e++) {
    float wv = cnorm[e];
    float2 sv = xb[csrc[e]];
    a0 += wv * sv.x;
    a1 += wv * sv.y;
  }
  ((float2*)ax)[g] = make_float2(a0, a1);
}

// h1 = relu(ax @ W1 + b1)   (K=2, trivial)
__global__ __launch_bounds__(256) void k_g1(const float* __restrict__ ax,
                                            const float* __restrict__ W1,
                                            const float* __restrict__ b1,
                                            float* __restrict__ h1) {
  int g = blockIdx.x * 256 + threadIdx.x;  // 5,120,000 exact
  int row = g >> 6, c = g & 63;
  float2 a = ((const float2*)ax)[row];
  float v = a.x * W1[c] + a.y * W1[64 + c] + b1[c];
  h1[g] = fmaxf(v, 0.0f);
}

// ah[b,n,c] = dinv[n]^2*h1[b,n,c] + sum_e norm*h1[b,src,c]; wave per (b,n), lane=c
// blockIdx&7 -> batch (XCD L2 affinity: one 2.56MB batch slice per XCD)
__global__ __launch_bounds__(256) void k_agg64(const float* __restrict__ h1,
                                               const float* __restrict__ dinv,
                                               const int* __restrict__ rp,
                                               const int* __restrict__ csrc,
                                               const float* __restrict__ cnorm,
                                               float* __restrict__ ah) {
  int b = blockIdx.x & 7;
  int grp = blockIdx.x >> 3;                 // 0..2499
  int n = grp * 4 + (threadIdx.x >> 6);
  int c = threadIdx.x & 63;
  const float* hb = h1 + (size_t)b * N_NODES * HID;
  float di = dinv[n];
  float acc = di * di * hb[n * 64 + c];
  int e1 = rp[n + 1];
  for (int e = rp[n]; e < e1; e++) {
    acc += cnorm[e] * hb[csrc[e] * 64 + c];
  }
  ah[(size_t)b * N_NODES * HID + n * 64 + c] = acc;
}

// ---------------- GEMM: C[M x 64] = relu(concat(A0,A1,A2)[M x nseg*64] @ W[nseg*64 x 64] + bias) ----------------
// block: 64 rows x 64 cols, 256 threads, 4x4 microtile, BK=16 LDS staging.

__global__ __launch_bounds__(256) void k_gemm(const float* __restrict__ A0,
                                              const float* __restrict__ A1,
                                              const float* __restrict__ A2,
                                              const float* __restrict__ W,
                                              const float* __restrict__ bias,
                                              float* __restrict__ C, int nseg) {
  __shared__ __align__(16) float As[16 * 64];
  __shared__ __align__(16) float Ws[16 * 64];
  int tid = threadIdx.x;
  int rowBase = blockIdx.x * 64;
  int tx = tid & 15, ty = tid >> 4;
  int ra = tid >> 2, ka = (tid & 3) * 4;   // A staging: row ra, k chunk ka..ka+3
  int kw = tid >> 4, cw = (tid & 15) * 4;  // W staging
  float acc[4][4] = {{0.0f}};
  int nch = nseg * 4;
  for (int ch = 0; ch < nch; ch++) {
    int seg = ch >> 2;
    int colb = (ch & 3) * 16;
    const float* Ap = (seg == 0) ? A0 : ((seg == 1) ? A1 : A2);
    float4 av = *(const float4*)(Ap + (size_t)(rowBase + ra) * 64 + colb + ka);
    float4 wv = *(const float4*)(W + (size_t)(seg * 64 + colb + kw) * 64 + cw);
    __syncthreads();
    As[(ka + 0) * 64 + ra] = av.x;
    As[(ka + 1) * 64 + ra] = av.y;
    As[(ka + 2) * 64 + ra] = av.z;
    As[(ka + 3) * 64 + ra] = av.w;
    *(float4*)&Ws[kw * 64 + cw] = wv;
    __syncthreads();
    #pragma unroll
    for (int k = 0; k < 16; k++) {
      float4 a = *(const float4*)&As[k * 64 + 4 * ty];
      float4 w = *(const float4*)&Ws[k * 64 + 4 * tx];
      acc[0][0] += a.x * w.x; acc[0][1] += a.x * w.y; acc[0][2] += a.x * w.z; acc[0][3] += a.x * w.w;
      acc[1][0] += a.y * w.x; acc[1][1] += a.y * w.y; acc[1][2] += a.y * w.z; acc[1][3] += a.y * w.w;
      acc[2][0] += a.z * w.x; acc[2][1] += a.z * w.y; acc[2][2] += a.z * w.z; acc[2][3] += a.z * w.w;
      acc[3][0] += a.w * w.x; acc[3][1] += a.w * w.y; acc[3][2] += a.w * w.z; acc[3][3] += a.w * w.w;
    }
  }
  float4 bv = *(const float4*)(bias + 4 * tx);
  #pragma unroll
  for (int i = 0; i < 4; i++) {
    int row = rowBase + 4 * ty + i;
    float4 o;
    o.x = fmaxf(acc[i][0] + bv.x, 0.0f);
    o.y = fmaxf(acc[i][1] + bv.y, 0.0f);
    o.z = fmaxf(acc[i][2] + bv.z, 0.0f);
    o.w = fmaxf(acc[i][3] + bv.w, 0.0f);
    *(float4*)(C + (size_t)row * 64 + 4 * tx) = o;
  }
}

// out[row] = sum_c last[row,c]*ow[c] + ob   (wave per row)
__global__ __launch_bounds__(256) void k_final(const float* __restrict__ last,
                                               const float* __restrict__ ow,
                                               const float* __restrict__ ob,
                                               float* __restrict__ out) {
  int row = blockIdx.x * 4 + (threadIdx.x >> 6);
  int lane = threadIdx.x & 63;
  float v = last[(size_t)row * 64 + lane] * ow[lane];
  for (int off = 32; off > 0; off >>= 1) v += __shfl_down(v, off, 64);
  if (lane == 0) out[row] = v + ob[0];
}

// ---------------- launch ----------------

extern "C" void kernel_launch(void* const* d_in, const int* in_sizes, int n_in,
                              void* d_out, int out_size, void* d_ws, size_t ws_size,
                              hipStream_t stream) {
  const float* X    = (const float*)d_in[0];
  const int*   EI   = (const int*)  d_in[1];
  const float* EW   = (const float*)d_in[2];
  const float* W1   = (const float*)d_in[3];
  const float* B1   = (const float*)d_in[4];
  const float* W2   = (const float*)d_in[5];
  const float* B2   = (const float*)d_in[6];
  const float* TC1W = (const float*)d_in[7];
  const float* TC1B = (const float*)d_in[8];
  const float* TC2W = (const float*)d_in[9];
  const float* TC2B = (const float*)d_in[10];
  const float* OW   = (const float*)d_in[11];
  const float* OB   = (const float*)d_in[12];
  float* out = (float*)d_out;

  char* base = (char*)d_ws;
  size_t off = 0;
  auto alloc = [&](size_t bytes) -> char* {
    char* p = base + off;
    off += (bytes + 255) & ~(size_t)255;
    return p;
  };
  float* deg   = (float*)alloc(N_NODES * 4);
  float* dinv  = (float*)alloc(N_NODES * 4);
  int*   cnt   = (int*)  alloc(N_NODES * 4);
  int*   rp    = (int*)  alloc((N_NODES + 1) * 4);
  int*   cur   = (int*)  alloc(N_NODES * 4);
  int*   csrc  = (int*)  alloc(EDGES * 4);
  float* cnorm = (float*)alloc(EDGES * 4);
  float* p1    = (float*)alloc(12288 * 4);
  float* p2    = (float*)alloc(12288 * 4);
  float* ax    = (float*)alloc((size_t)BATCH * N_NODES * 2 * 4);
  const size_t HSZ = (size_t)BATCH * N_NODES * HID;  // 5,120,000 floats
  float* h1  = (float*)alloc(HSZ * 4);
  float* ah  = (float*)alloc(HSZ * 4);
  float* sp0 = (float*)alloc(HSZ * 4);
  float* sp1 = (float*)alloc(HSZ * 4);
  float* sp2 = (float*)alloc(HSZ * 4);

  hipMemsetAsync(deg, 0, N_NODES * 4, stream);
  hipMemsetAsync(cnt, 0, N_NODES * 4, stream);
  k_deg_hist<<<625, 256, 0, stream>>>(EI, EW, deg, cnt);
  k_dinv<<<40, 256, 0, stream>>>(deg, dinv);
  k_scan<<<1, 1024, 0, stream>>>(cnt, rp, cur);
  k_fill<<<625, 256, 0, stream>>>(EI, EW, dinv, cur, csrc, cnorm);
  k_pack<<<96, 256, 0, stream>>>(TC1W, TC2W, p1, p2);

  // Only t = 9,10,11 feed the final output.
  float* sps[3] = {sp0, sp1, sp2};
  for (int ti = 0; ti < 3; ti++) {
    int t = 9 + ti;
    k_agg2<<<313, 256, 0, stream>>>(X, t, dinv, rp, csrc, cnorm, ax);
    k_g1<<<20000, 256, 0, stream>>>(ax, W1, B1, h1);
    k_agg64<<<20000, 256, 0, stream>>>(h1, dinv, rp, csrc, cnorm, ah);
    k_gemm<<<1250, 256, 0, stream>>>(ah, nullptr, nullptr, W2, B2, sps[ti], 1);
  }
  // conv1: t1[11] = relu([sp(10) sp(11)] @ p1[0:128] + tc1_b)  -> h1 (free)
  k_gemm<<<1250, 256, 0, stream>>>(sp1, sp2, nullptr, p1, TC1B, h1, 2);
  // conv1: t1[10] = relu([sp(9) sp(10) sp(11)] @ p1[0:192] + tc1_b) -> ah (free)
  k_gemm<<<1250, 256, 0, stream>>>(sp0, sp1, sp2, p1, TC1B, ah, 3);
  // conv2 @ t=11: last = relu([t1(10) t1(11)] @ p2[0:128] + tc2_b) -> sp0 (free)
  k_gemm<<<1250, 256, 0, stream>>>(ah, h1, nullptr, p2, TC2B, sp0, 2);
  // out = last @ out_w + out_b
  k_final<<<20000, 256, 0, stream>>>(sp0, OW, OB, out);
}

// Round 2
// 404.853 us; speedup vs baseline: 1.3909x; 1.3909x over previous
//
#include <hip/hip_runtime.h>

#define N_NODES 10000
#define EDGES   160000
#define BATCH   8
#define TT      12
#define HID     64
#define EPAD    230000   // 160000 + 10000*7 worst-case pad-to-8

// ---------------- CSR build ----------------

__global__ __launch_bounds__(256) void k_deg_hist(const int* __restrict__ ei,
                                                  const float* __restrict__ ew,
                                                  float* __restrict__ deg,
                                                  int* __restrict__ cnt) {
  int g = blockIdx.x * 256 + threadIdx.x;
  if (g < EDGES) {
    int d = ei[EDGES + g];
    atomicAdd(&deg[d], ew[g]);
    atomicAdd(&cnt[d], 1);
  }
}

__global__ __launch_bounds__(256) void k_dinv(const float* __restrict__ deg,
                                              float* __restrict__ dinv) {
  int g = blockIdx.x * 256 + threadIdx.x;
  if (g < N_NODES) dinv[g] = 1.0f / sqrtf(deg[g] + 1.0f);  // +1 = self-loop weight
}

// prefix scan of per-node counts PADDED UP TO MULTIPLE OF 8
__global__ __launch_bounds__(1024) void k_scan(const int* __restrict__ cnt,
                                               int* __restrict__ row_ptr,
                                               int* __restrict__ cursor) {
  __shared__ int part[1024];
  int tid = threadIdx.x;
  int base = tid * 10;
  int local[10];
  int s = 0;
  #pragma unroll
  for (int j = 0; j < 10; j++) {
    int idx = base + j;
    int v = (idx < N_NODES) ? cnt[idx] : 0;
    v = (v + 7) & ~7;              // pad each node's list to multiple of 8
    local[j] = s;
    s += v;
  }
  part[tid] = s;
  __syncthreads();
  for (int off = 1; off < 1024; off <<= 1) {
    int v = (tid >= off) ? part[tid - off] : 0;
    __syncthreads();
    part[tid] += v;
    __syncthreads();
  }
  int pre = (tid > 0) ? part[tid - 1] : 0;
  #pragma unroll
  for (int j = 0; j < 10; j++) {
    int idx = base + j;
    if (idx < N_NODES) {
      int rpv = pre + local[j];
      row_ptr[idx] = rpv;
      cursor[idx]  = rpv;
    }
  }
  if (tid == 0) row_ptr[N_NODES] = part[1023];
}

__global__ __launch_bounds__(256) void k_fill(const int* __restrict__ ei,
                                              const float* __restrict__ ew,
                                              const float* __restrict__ dinv,
                                              int* __restrict__ cursor,
                                              int* __restrict__ csrc,
                                              float* __restrict__ cnorm) {
  int g = blockIdx.x * 256 + threadIdx.x;
  if (g < EDGES) {
    int s = ei[g], d = ei[EDGES + g];
    int slot = atomicAdd(&cursor[d], 1);
    csrc[slot]  = s;
    cnorm[slot] = dinv[s] * ew[g] * dinv[d];
  }
}

// fill pad slots (cursor[n]..rp[n+1]) with src=0, w=0
__global__ __launch_bounds__(256) void k_padfill(const int* __restrict__ rp,
                                                 const int* __restrict__ cursor,
                                                 int* __restrict__ csrc,
                                                 float* __restrict__ cnorm) {
  int n = blockIdx.x * 256 + threadIdx.x;
  if (n >= N_NODES) return;
  int e = cursor[n], e1 = rp[n + 1];
  for (; e < e1; e++) { csrc[e] = 0; cnorm[e] = 0.0f; }
}

// pack conv weights:
//  p1c [192][128]: row kk: t3=kk>>6 (sp seg t=9+t3), i=kk&63; col: half=col>>6, o=col&63
//    half0 (t'=10): w[t3];  half1 (t'=11): t3==0 ? 0 : w[t3-1]
//  p2c [128][64]:  row kk: g=kk>>6 (t1 half, t'=10+g), i=kk&63; col o: w[g]
//  pb1 [128] = tc1_b duplicated
__global__ __launch_bounds__(256) void k_pack(const float* __restrict__ tc1w,
                                              const float* __restrict__ tc2w,
                                              const float* __restrict__ tc1b,
                                              float* __restrict__ p1c,
                                              float* __restrict__ p2c,
                                              float* __restrict__ pb1) {
  int g = blockIdx.x * 256 + threadIdx.x;
  if (g < 24576) {
    int kk = g >> 7, col = g & 127;
    int t3 = kk >> 6, i = kk & 63;
    int half = col >> 6, o = col & 63;
    float v;
    if (half == 0) v = tc1w[o * 192 + i * 3 + t3];
    else           v = (t3 == 0) ? 0.0f : tc1w[o * 192 + i * 3 + (t3 - 1)];
    p1c[g] = v;
  } else if (g < 24576 + 8192) {
    int r = g - 24576;
    int kk = r >> 6, o = r & 63;
    int gk = kk >> 6, i = kk & 63;
    p2c[r] = tc2w[o * 192 + i * 3 + gk];
  } else if (g < 24576 + 8192 + 128) {
    int r = g - 24576 - 8192;
    pb1[r] = tc1b[r & 63];
  }
}

// ---------------- GCN ----------------

// aggregate raw X for t=9,10,11: ax[(b*N+n)*3+t3] (float2)
__global__ __launch_bounds__(256) void k_agg2(const float* __restrict__ X,
                                              const float* __restrict__ dinv,
                                              const int* __restrict__ rp,
                                              const int* __restrict__ csrc,
                                              const float* __restrict__ cnorm,
                                              float* __restrict__ ax) {
  int g = blockIdx.x * 256 + threadIdx.x;
  if (g >= BATCH * N_NODES) return;
  int n = g % N_NODES, b = g / N_NODES;
  const float2* x0 = (const float2*)(X + (size_t)(b * TT + 9)  * N_NODES * 2);
  const float2* x1 = (const float2*)(X + (size_t)(b * TT + 10) * N_NODES * 2);
  const float2* x2 = (const float2*)(X + (size_t)(b * TT + 11) * N_NODES * 2);
  float di = dinv[n];
  float s2 = di * di;
  float2 v0 = x0[n], v1 = x1[n], v2 = x2[n];
  float a0x = s2 * v0.x, a0y = s2 * v0.y;
  float a1x = s2 * v1.x, a1y = s2 * v1.y;
  float a2x = s2 * v2.x, a2y = s2 * v2.y;
  int e1 = rp[n + 1];
  for (int e = rp[n]; e < e1; e++) {
    float w = cnorm[e];
    int s = csrc[e];
    float2 s0 = x0[s], s1 = x1[s], s2v = x2[s];
    a0x += w * s0.x;  a0y += w * s0.y;
    a1x += w * s1.x;  a1y += w * s1.y;
    a2x += w * s2v.x; a2y += w * s2v.y;
  }
  float2* o = (float2*)ax + (size_t)g * 3;
  o[0] = make_float2(a0x, a0y);
  o[1] = make_float2(a1x, a1y);
  o[2] = make_float2(a2x, a2y);
}

// h1 = relu(ax @ W1 + b1), rows = (b,n,t3), 64 cols
__global__ __launch_bounds__(256) void k_g1(const float* __restrict__ ax,
                                            const float* __restrict__ W1,
                                            const float* __restrict__ b1,
                                            float* __restrict__ h1) {
  int g = blockIdx.x * 256 + threadIdx.x;  // 15,360,000 exact
  int row = g >> 6, c = g & 63;
  float2 a = ((const float2*)ax)[row];
  float v = a.x * W1[c] + a.y * W1[64 + c] + b1[c];
  h1[g] = fmaxf(v, 0.0f);
}

// ah[(b,n,t3)][c] = dinv[n]^2*h1[...] + sum_e norm*h1[b,src,t3,c]
// wave per (b,n); 3 independent gathers per edge; indices shfl-broadcast.
__global__ __launch_bounds__(256) void k_agg3t(const float* __restrict__ h1,
                                               const float* __restrict__ dinv,
                                               const int* __restrict__ rp,
                                               const int* __restrict__ csrc,
                                               const float* __restrict__ cnorm,
                                               float* __restrict__ ah) {
  int b = blockIdx.x & 7;                    // XCD L2 affinity
  int grp = blockIdx.x >> 3;                 // 0..2499
  int n = grp * 4 + (threadIdx.x >> 6);
  int c = threadIdx.x & 63;
  const float* hb = h1 + (size_t)b * N_NODES * 192;
  float di = dinv[n];
  float s2 = di * di;
  const float* hn = hb + (size_t)n * 192;
  float acc0 = s2 * hn[c];
  float acc1 = s2 * hn[64 + c];
  float acc2 = s2 * hn[128 + c];
  int e0 = rp[n], e1 = rp[n + 1];
  for (int base = e0; base < e1; base += 64) {
    int idx = base + c;
    bool valid = idx < e1;
    int   sv = valid ? csrc[idx]  : 0;
    float wv = valid ? cnorm[idx] : 0.0f;
    int m = e1 - base; if (m > 64) m = 64;   // m is a multiple of 8
    for (int j = 0; j < m; j += 8) {
      #pragma unroll
      for (int u = 0; u < 8; u++) {
        int   sj = __shfl(sv, j + u, 64);
        float wj = __shfl(wv, j + u, 64);
        const float* hs = hb + (size_t)sj * 192;
        acc0 += wj * hs[c];
        acc1 += wj * hs[64 + c];
        acc2 += wj * hs[128 + c];
      }
    }
  }
  size_t ob = ((size_t)(b * N_NODES + n)) * 192 + c;
  ah[ob]       = acc0;
  ah[ob + 64]  = acc1;
  ah[ob + 128] = acc2;
}

// ---------------- GEMM: C[128 x 64] tile, 128 threads, 8x8 microtile, BK=16 ----------------
// C = relu(A[M x K] @ W[K x N] + bias), row strides lda/ldw/ldc; grid.y picks 64-col block.

__global__ __launch_bounds__(128, 3) void k_gemm(const float* __restrict__ A, int lda,
                                                 const float* __restrict__ W, int ldw,
                                                 const float* __restrict__ bias,
                                                 float* __restrict__ C, int ldc, int K) {
  __shared__ __align__(16) float As[16 * 128];
  __shared__ __align__(16) float Ws[16 * 64];
  int tid = threadIdx.x;
  size_t rowBase = (size_t)blockIdx.x * 128;
  int colBase = blockIdx.y * 64;
  int ra = tid >> 2, kc = (tid & 3) * 4;      // A staging: rows ra+{0,32,64,96}
  int kw = tid >> 4, cw = (tid & 15) * 4;     // W staging: k rows kw, kw+8
  int tr = tid >> 3, tc = tid & 7;            // microtile coords
  float acc[8][8] = {{0.0f}};
  for (int k0 = 0; k0 < K; k0 += 16) {
    float4 a[4];
    #pragma unroll
    for (int i = 0; i < 4; i++)
      a[i] = *(const float4*)(A + (rowBase + ra + 32 * i) * lda + k0 + kc);
    float4 wa = *(const float4*)(W + (size_t)(k0 + kw) * ldw + colBase + cw);
    float4 wb = *(const float4*)(W + (size_t)(k0 + kw + 8) * ldw + colBase + cw);
    __syncthreads();
    #pragma unroll
    for (int i = 0; i < 4; i++) {
      int r = ra + 32 * i;
      As[(kc + 0) * 128 + r] = a[i].x;
      As[(kc + 1) * 128 + r] = a[i].y;
      As[(kc + 2) * 128 + r] = a[i].z;
      As[(kc + 3) * 128 + r] = a[i].w;
    }
    *(float4*)&Ws[kw * 64 + cw] = wa;
    *(float4*)&Ws[(kw + 8) * 64 + cw] = wb;
    __syncthreads();
    #pragma unroll
    for (int k = 0; k < 16; k++) {
      float4 a0 = *(const float4*)&As[k * 128 + 8 * tr];
      float4 a1 = *(const float4*)&As[k * 128 + 8 * tr + 4];
      float4 w0 = *(const float4*)&Ws[k * 64 + 8 * tc];
      float4 w1 = *(const float4*)&Ws[k * 64 + 8 * tc + 4];
      float av[8] = {a0.x, a0.y, a0.z, a0.w, a1.x, a1.y, a1.z, a1.w};
      float wv[8] = {w0.x, w0.y, w0.z, w0.w, w1.x, w1.y, w1.z, w1.w};
      #pragma unroll
      for (int i = 0; i < 8; i++)
        #pragma unroll
        for (int j = 0; j < 8; j++)
          acc[i][j] += av[i] * wv[j];
    }
  }
  float4 b0 = *(const float4*)(bias + colBase + 8 * tc);
  float4 b1 = *(const float4*)(bias + colBase + 8 * tc + 4);
  float bb[8] = {b0.x, b0.y, b0.z, b0.w, b1.x, b1.y, b1.z, b1.w};
  #pragma unroll
  for (int i = 0; i < 8; i++) {
    size_t row = rowBase + 8 * tr + i;
    float* cp = C + row * ldc + colBase + 8 * tc;
    float4 o0, o1;
    o0.x = fmaxf(acc[i][0] + bb[0], 0.0f);
    o0.y = fmaxf(acc[i][1] + bb[1], 0.0f);
    o0.z = fmaxf(acc[i][2] + bb[2], 0.0f);
    o0.w = fmaxf(acc[i][3] + bb[3], 0.0f);
    o1.x = fmaxf(acc[i][4] + bb[4], 0.0f);
    o1.y = fmaxf(acc[i][5] + bb[5], 0.0f);
    o1.z = fmaxf(acc[i][6] + bb[6], 0.0f);
    o1.w = fmaxf(acc[i][7] + bb[7], 0.0f);
    *(float4*)cp = o0;
    *(float4*)(cp + 4) = o1;
  }
}

// out[row] = sum_c last[row,c]*ow[c] + ob   (wave per row)
__global__ __launch_bounds__(256) void k_final(const float* __restrict__ last,
                                               const float* __restrict__ ow,
                                               const float* __restrict__ ob,
                                               float* __restrict__ out) {
  int row = blockIdx.x * 4 + (threadIdx.x >> 6);
  int lane = threadIdx.x & 63;
  float v = last[(size_t)row * 64 + lane] * ow[lane];
  for (int off = 32; off > 0; off >>= 1) v += __shfl_down(v, off, 64);
  if (lane == 0) out[row] = v + ob[0];
}

// ---------------- launch ----------------

extern "C" void kernel_launch(void* const* d_in, const int* in_sizes, int n_in,
                              void* d_out, int out_size, void* d_ws, size_t ws_size,
                              hipStream_t stream) {
  const float* X    = (const float*)d_in[0];
  const int*   EI   = (const int*)  d_in[1];
  const float* EW   = (const float*)d_in[2];
  const float* W1   = (const float*)d_in[3];
  const float* B1   = (const float*)d_in[4];
  const float* W2   = (const float*)d_in[5];
  const float* B2   = (const float*)d_in[6];
  const float* TC1W = (const float*)d_in[7];
  const float* TC1B = (const float*)d_in[8];
  const float* TC2W = (const float*)d_in[9];
  const float* TC2B = (const float*)d_in[10];
  const float* OW   = (const float*)d_in[11];
  const float* OB   = (const float*)d_in[12];
  float* out = (float*)d_out;

  char* base = (char*)d_ws;
  size_t off = 0;
  auto alloc = [&](size_t bytes) -> char* {
    char* p = base + off;
    off += (bytes + 255) & ~(size_t)255;
    return p;
  };
  float* deg   = (float*)alloc(N_NODES * 4);
  float* dinv  = (float*)alloc(N_NODES * 4);
  int*   cnt   = (int*)  alloc(N_NODES * 4);
  int*   rp    = (int*)  alloc((N_NODES + 1) * 4);
  int*   cur   = (int*)  alloc(N_NODES * 4);
  int*   csrc  = (int*)  alloc(EPAD * 4);
  float* cnorm = (float*)alloc(EPAD * 4);
  float* p1c   = (float*)alloc(192 * 128 * 4);
  float* p2c   = (float*)alloc(128 * 64 * 4);
  float* pb1   = (float*)alloc(128 * 4);
  float* ax    = (float*)alloc((size_t)BATCH * N_NODES * 3 * 2 * 4);
  // big buffers: each 15,360,000 floats (= 80000*192 = 240000*64)
  const size_t BIG = (size_t)80000 * 192;
  float* h1buf = (float*)alloc(BIG * 4);   // h1; later t1 (80000x128) + last (80000x64)
  float* ahbuf = (float*)alloc(BIG * 4);   // ah; W2-GEMM runs in-place -> sp

  float* h1   = h1buf;
  float* ah   = ahbuf;
  float* sp   = ahbuf;                       // in-place W2 GEMM output
  float* t1   = h1buf;                       // 80000 x 128
  float* last = h1buf + (size_t)80000 * 128; // 80000 x 64

  hipMemsetAsync(deg, 0, N_NODES * 4, stream);
  hipMemsetAsync(cnt, 0, N_NODES * 4, stream);
  k_deg_hist<<<625, 256, 0, stream>>>(EI, EW, deg, cnt);
  k_dinv<<<40, 256, 0, stream>>>(deg, dinv);
  k_scan<<<1, 1024, 0, stream>>>(cnt, rp, cur);
  k_fill<<<625, 256, 0, stream>>>(EI, EW, dinv, cur, csrc, cnorm);
  k_padfill<<<40, 256, 0, stream>>>(rp, cur, csrc, cnorm);
  k_pack<<<129, 256, 0, stream>>>(TC1W, TC2W, TC1B, p1c, p2c, pb1);

  k_agg2<<<313, 256, 0, stream>>>(X, dinv, rp, csrc, cnorm, ax);
  k_g1<<<60000, 256, 0, stream>>>(ax, W1, B1, h1);
  k_agg3t<<<20000, 256, 0, stream>>>(h1, dinv, rp, csrc, cnorm, ah);

  // sp = relu(ah @ W2 + b2): M=240000, K=64, N=64 (in-place on ahbuf)
  k_gemm<<<dim3(1875, 1), 128, 0, stream>>>(ah, 64, W2, 64, B2, sp, 64, 64);
  // t1 = relu(sp-rows @ p1c + pb1): M=80000, K=192, N=128 (both conv1 outputs)
  k_gemm<<<dim3(625, 2), 128, 0, stream>>>(sp, 192, p1c, 128, pb1, t1, 128, 192);
  // last = relu(t1 @ p2c + tc2_b): M=80000, K=128, N=64
  k_gemm<<<dim3(625, 1), 128, 0, stream>>>(t1, 128, p2c, 64, TC2B, last, 64, 128);

  k_final<<<20000, 256, 0, stream>>>(last, OW, OB, out);
}

// Round 3
// 386.539 us; speedup vs baseline: 1.4569x; 1.0474x over previous
//
#include <hip/hip_runtime.h>

#define N_NODES 10000
#define EDGES   160000
#define BATCH   8
#define TT      12
#define HID     64
#define EPAD    230000   // 160000 + 10000*7 worst-case pad-to-8

// ---------------- CSR build ----------------

__global__ __launch_bounds__(256) void k_deg_hist(const int* __restrict__ ei,
                                                  const float* __restrict__ ew,
                                                  float* __restrict__ deg,
                                                  int* __restrict__ cnt) {
  int g = blockIdx.x * 256 + threadIdx.x;
  if (g < EDGES) {
    int d = ei[EDGES + g];
    atomicAdd(&deg[d], ew[g]);
    atomicAdd(&cnt[d], 1);
  }
}

__global__ __launch_bounds__(256) void k_dinv(const float* __restrict__ deg,
                                              float* __restrict__ dinv) {
  int g = blockIdx.x * 256 + threadIdx.x;
  if (g < N_NODES) dinv[g] = 1.0f / sqrtf(deg[g] + 1.0f);  // +1 = self-loop weight
}

// prefix scan of per-node counts PADDED UP TO MULTIPLE OF 8
__global__ __launch_bounds__(1024) void k_scan(const int* __restrict__ cnt,
                                               int* __restrict__ row_ptr,
                                               int* __restrict__ cursor) {
  __shared__ int part[1024];
  int tid = threadIdx.x;
  int base = tid * 10;
  int local[10];
  int s = 0;
  #pragma unroll
  for (int j = 0; j < 10; j++) {
    int idx = base + j;
    int v = (idx < N_NODES) ? cnt[idx] : 0;
    v = (v + 7) & ~7;              // pad each node's list to multiple of 8
    local[j] = s;
    s += v;
  }
  part[tid] = s;
  __syncthreads();
  for (int off = 1; off < 1024; off <<= 1) {
    int v = (tid >= off) ? part[tid - off] : 0;
    __syncthreads();
    part[tid] += v;
    __syncthreads();
  }
  int pre = (tid > 0) ? part[tid - 1] : 0;
  #pragma unroll
  for (int j = 0; j < 10; j++) {
    int idx = base + j;
    if (idx < N_NODES) {
      int rpv = pre + local[j];
      row_ptr[idx] = rpv;
      cursor[idx]  = rpv;
    }
  }
  if (tid == 0) row_ptr[N_NODES] = part[1023];
}

__global__ __launch_bounds__(256) void k_fill(const int* __restrict__ ei,
                                              const float* __restrict__ ew,
                                              const float* __restrict__ dinv,
                                              int* __restrict__ cursor,
                                              int* __restrict__ csrc,
                                              float* __restrict__ cnorm) {
  int g = blockIdx.x * 256 + threadIdx.x;
  if (g < EDGES) {
    int s = ei[g], d = ei[EDGES + g];
    int slot = atomicAdd(&cursor[d], 1);
    csrc[slot]  = s;
    cnorm[slot] = dinv[s] * ew[g] * dinv[d];
  }
}

// fill pad slots (cursor[n]..rp[n+1]) with src=0, w=0
__global__ __launch_bounds__(256) void k_padfill(const int* __restrict__ rp,
                                                 const int* __restrict__ cursor,
                                                 int* __restrict__ csrc,
                                                 float* __restrict__ cnorm) {
  int n = blockIdx.x * 256 + threadIdx.x;
  if (n >= N_NODES) return;
  int e = cursor[n], e1 = rp[n + 1];
  for (; e < e1; e++) { csrc[e] = 0; cnorm[e] = 0.0f; }
}

// pack conv weights:
//  p1c [192][128]: row kk: t3=kk>>6 (sp seg t=9+t3), i=kk&63; col: half=col>>6, o=col&63
//    half0 (t'=10): w[t3];  half1 (t'=11): t3==0 ? 0 : w[t3-1]
//  p2c [128][64]:  row kk: g=kk>>6 (t1 half, t'=10+g), i=kk&63; col o: w[g]
//  pb1 [128] = tc1_b duplicated
__global__ __launch_bounds__(256) void k_pack(const float* __restrict__ tc1w,
                                              const float* __restrict__ tc2w,
                                              const float* __restrict__ tc1b,
                                              float* __restrict__ p1c,
                                              float* __restrict__ p2c,
                                              float* __restrict__ pb1) {
  int g = blockIdx.x * 256 + threadIdx.x;
  if (g < 24576) {
    int kk = g >> 7, col = g & 127;
    int t3 = kk >> 6, i = kk & 63;
    int half = col >> 6, o = col & 63;
    float v;
    if (half == 0) v = tc1w[o * 192 + i * 3 + t3];
    else           v = (t3 == 0) ? 0.0f : tc1w[o * 192 + i * 3 + (t3 - 1)];
    p1c[g] = v;
  } else if (g < 24576 + 8192) {
    int r = g - 24576;
    int kk = r >> 6, o = r & 63;
    int gk = kk >> 6, i = kk & 63;
    p2c[r] = tc2w[o * 192 + i * 3 + gk];
  } else if (g < 24576 + 8192 + 128) {
    int r = g - 24576 - 8192;
    pb1[r] = tc1b[r & 63];
  }
}

// ---------------- GCN layer 1: fused agg(X) @ W1 + b1, relu -> h1[b][n][t3*64+c] ----------------
// wave per (b,n): lanes edge-parallel (coalesced csrc/cnorm), butterfly-reduce 6 partials,
// then per-lane W1 epilogue (K=2).

__global__ __launch_bounds__(256) void k_aggg1(const float* __restrict__ X,
                                               const float* __restrict__ dinv,
                                               const int* __restrict__ rp,
                                               const int* __restrict__ csrc,
                                               const float* __restrict__ cnorm,
                                               const float* __restrict__ W1,
                                               const float* __restrict__ b1,
                                               float* __restrict__ h1) {
  int b = blockIdx.x & 7;                    // batch -> XCD affinity
  int grp = blockIdx.x >> 3;                 // 0..2499
  int n = grp * 4 + (threadIdx.x >> 6);
  int lane = threadIdx.x & 63;
  const float2* x0 = (const float2*)(X + (size_t)(b * TT + 9)  * N_NODES * 2);
  const float2* x1 = (const float2*)(X + (size_t)(b * TT + 10) * N_NODES * 2);
  const float2* x2 = (const float2*)(X + (size_t)(b * TT + 11) * N_NODES * 2);
  float a0x = 0.f, a0y = 0.f, a1x = 0.f, a1y = 0.f, a2x = 0.f, a2y = 0.f;
  int e0 = rp[n], e1 = rp[n + 1];
  for (int idx = e0 + lane; idx < e1; idx += 64) {
    float w = cnorm[idx];
    int s = csrc[idx];
    float2 s0 = x0[s], s1 = x1[s], s2v = x2[s];
    a0x += w * s0.x;  a0y += w * s0.y;
    a1x += w * s1.x;  a1y += w * s1.y;
    a2x += w * s2v.x; a2y += w * s2v.y;
  }
  if (lane == 0) {  // self-loop term
    float di = dinv[n];
    float sd = di * di;
    float2 v0 = x0[n], v1 = x1[n], v2 = x2[n];
    a0x += sd * v0.x; a0y += sd * v0.y;
    a1x += sd * v1.x; a1y += sd * v1.y;
    a2x += sd * v2.x; a2y += sd * v2.y;
  }
  #pragma unroll
  for (int off = 32; off > 0; off >>= 1) {
    a0x += __shfl_xor(a0x, off, 64);
    a0y += __shfl_xor(a0y, off, 64);
    a1x += __shfl_xor(a1x, off, 64);
    a1y += __shfl_xor(a1y, off, 64);
    a2x += __shfl_xor(a2x, off, 64);
    a2y += __shfl_xor(a2y, off, 64);
  }
  int c = lane;
  float w0 = W1[c], w1 = W1[64 + c], bc = b1[c];
  size_t ob = ((size_t)(b * N_NODES + n)) * 192 + c;
  h1[ob]       = fmaxf(a0x * w0 + a0y * w1 + bc, 0.0f);
  h1[ob + 64]  = fmaxf(a1x * w0 + a1y * w1 + bc, 0.0f);
  h1[ob + 128] = fmaxf(a2x * w0 + a2y * w1 + bc, 0.0f);
}

// ---------------- GCN layer 2 aggregation, t3-sliced for L2 residency ----------------
// blockIdx = ((t3*2500 + grp)*8) + b : b -> XCD, t3 slowest so each XCD's live
// gather slice is 10000 x 256B = 2.56 MB < 4 MiB L2.
__global__ __launch_bounds__(256) void k_agg1t(const float* __restrict__ h1,
                                               const float* __restrict__ dinv,
                                               const int* __restrict__ rp,
                                               const int* __restrict__ csrc,
                                               const float* __restrict__ cnorm,
                                               float* __restrict__ ah) {
  int b = blockIdx.x & 7;
  int r = blockIdx.x >> 3;                   // 0..7499
  int t3 = r / 2500;
  int grp = r % 2500;
  int n = grp * 4 + (threadIdx.x >> 6);
  int c = threadIdx.x & 63;
  const float* hb = h1 + (size_t)b * N_NODES * 192 + t3 * 64;
  float di = dinv[n];
  float acc = di * di * hb[(size_t)n * 192 + c];
  int e0 = rp[n], e1 = rp[n + 1];
  for (int base = e0; base < e1; base += 64) {
    int idx = base + c;
    bool valid = idx < e1;
    int   sv = valid ? csrc[idx]  : 0;
    float wv = valid ? cnorm[idx] : 0.0f;
    int m = e1 - base; if (m > 64) m = 64;   // multiple of 8
    for (int j = 0; j < m; j += 8) {
      #pragma unroll
      for (int u = 0; u < 8; u++) {
        int   sj = __shfl(sv, j + u, 64);
        float wj = __shfl(wv, j + u, 64);
        acc += wj * hb[(size_t)sj * 192 + c];
      }
    }
  }
  ah[((size_t)(b * N_NODES + n)) * 192 + t3 * 64 + c] = acc;
}

// ---------------- GEMM: C[128 x 64] tile, 128 threads, 8x8 microtile, BK=16 ----------------

__global__ __launch_bounds__(128, 3) void k_gemm(const float* __restrict__ A, int lda,
                                                 const float* __restrict__ W, int ldw,
                                                 const float* __restrict__ bias,
                                                 float* __restrict__ C, int ldc, int K) {
  __shared__ __align__(16) float As[16 * 128];
  __shared__ __align__(16) float Ws[16 * 64];
  int tid = threadIdx.x;
  size_t rowBase = (size_t)blockIdx.x * 128;
  int colBase = blockIdx.y * 64;
  int ra = tid >> 2, kc = (tid & 3) * 4;
  int kw = tid >> 4, cw = (tid & 15) * 4;
  int tr = tid >> 3, tc = tid & 7;
  float acc[8][8] = {{0.0f}};
  for (int k0 = 0; k0 < K; k0 += 16) {
    float4 a[4];
    #pragma unroll
    for (int i = 0; i < 4; i++)
      a[i] = *(const float4*)(A + (rowBase + ra + 32 * i) * lda + k0 + kc);
    float4 wa = *(const float4*)(W + (size_t)(k0 + kw) * ldw + colBase + cw);
    float4 wb = *(const float4*)(W + (size_t)(k0 + kw + 8) * ldw + colBase + cw);
    __syncthreads();
    #pragma unroll
    for (int i = 0; i < 4; i++) {
      int r = ra + 32 * i;
      As[(kc + 0) * 128 + r] = a[i].x;
      As[(kc + 1) * 128 + r] = a[i].y;
      As[(kc + 2) * 128 + r] = a[i].z;
      As[(kc + 3) * 128 + r] = a[i].w;
    }
    *(float4*)&Ws[kw * 64 + cw] = wa;
    *(float4*)&Ws[(kw + 8) * 64 + cw] = wb;
    __syncthreads();
    #pragma unroll
    for (int k = 0; k < 16; k++) {
      float4 a0 = *(const float4*)&As[k * 128 + 8 * tr];
      float4 a1 = *(const float4*)&As[k * 128 + 8 * tr + 4];
      float4 w0 = *(const float4*)&Ws[k * 64 + 8 * tc];
      float4 w1 = *(const float4*)&Ws[k * 64 + 8 * tc + 4];
      float av[8] = {a0.x, a0.y, a0.z, a0.w, a1.x, a1.y, a1.z, a1.w};
      float wv[8] = {w0.x, w0.y, w0.z, w0.w, w1.x, w1.y, w1.z, w1.w};
      #pragma unroll
      for (int i = 0; i < 8; i++)
        #pragma unroll
        for (int j = 0; j < 8; j++)
          acc[i][j] += av[i] * wv[j];
    }
  }
  float4 b0 = *(const float4*)(bias + colBase + 8 * tc);
  float4 b1 = *(const float4*)(bias + colBase + 8 * tc + 4);
  float bb[8] = {b0.x, b0.y, b0.z, b0.w, b1.x, b1.y, b1.z, b1.w};
  #pragma unroll
  for (int i = 0; i < 8; i++) {
    size_t row = rowBase + 8 * tr + i;
    float* cp = C + row * ldc + colBase + 8 * tc;
    float4 o0, o1;
    o0.x = fmaxf(acc[i][0] + bb[0], 0.0f);
    o0.y = fmaxf(acc[i][1] + bb[1], 0.0f);
    o0.z = fmaxf(acc[i][2] + bb[2], 0.0f);
    o0.w = fmaxf(acc[i][3] + bb[3], 0.0f);
    o1.x = fmaxf(acc[i][4] + bb[4], 0.0f);
    o1.y = fmaxf(acc[i][5] + bb[5], 0.0f);
    o1.z = fmaxf(acc[i][6] + bb[6], 0.0f);
    o1.w = fmaxf(acc[i][7] + bb[7], 0.0f);
    *(float4*)cp = o0;
    *(float4*)(cp + 4) = o1;
  }
}

// conv2 GEMM fused with final matvec: out[row] = dot(relu(A@W + bias), ow) + ob
// A: 80000 x 128 (t1), W: p2c 128x64, K=128, N=64.
__global__ __launch_bounds__(128, 3) void k_gemm_out(const float* __restrict__ A,
                                                     const float* __restrict__ W,
                                                     const float* __restrict__ bias,
                                                     const float* __restrict__ ow,
                                                     const float* __restrict__ obp,
                                                     float* __restrict__ out) {
  __shared__ __align__(16) float As[16 * 128];
  __shared__ __align__(16) float Ws[16 * 64];
  int tid = threadIdx.x;
  size_t rowBase = (size_t)blockIdx.x * 128;
  int ra = tid >> 2, kc = (tid & 3) * 4;
  int kw = tid >> 4, cw = (tid & 15) * 4;
  int tr = tid >> 3, tc = tid & 7;
  float acc[8][8] = {{0.0f}};
  for (int k0 = 0; k0 < 128; k0 += 16) {
    float4 a[4];
    #pragma unroll
    for (int i = 0; i < 4; i++)
      a[i] = *(const float4*)(A + (rowBase + ra + 32 * i) * 128 + k0 + kc);
    float4 wa = *(const float4*)(W + (size_t)(k0 + kw) * 64 + cw);
    float4 wb = *(const float4*)(W + (size_t)(k0 + kw + 8) * 64 + cw);
    __syncthreads();
    #pragma unroll
    for (int i = 0; i < 4; i++) {
      int r = ra + 32 * i;
      As[(kc + 0) * 128 + r] = a[i].x;
      As[(kc + 1) * 128 + r] = a[i].y;
      As[(kc + 2) * 128 + r] = a[i].z;
      As[(kc + 3) * 128 + r] = a[i].w;
    }
    *(float4*)&Ws[kw * 64 + cw] = wa;
    *(float4*)&Ws[(kw + 8) * 64 + cw] = wb;
    __syncthreads();
    #pragma unroll
    for (int k = 0; k < 16; k++) {
      float4 a0 = *(const float4*)&As[k * 128 + 8 * tr];
      float4 a1 = *(const float4*)&As[k * 128 + 8 * tr + 4];
      float4 w0 = *(const float4*)&Ws[k * 64 + 8 * tc];
      float4 w1 = *(const float4*)&Ws[k * 64 + 8 * tc + 4];
      float av[8] = {a0.x, a0.y, a0.z, a0.w, a1.x, a1.y, a1.z, a1.w};
      float wv[8] = {w0.x, w0.y, w0.z, w0.w, w1.x, w1.y, w1.z, w1.w};
      #pragma unroll
      for (int i = 0; i < 8; i++)
        #pragma unroll
        for (int j = 0; j < 8; j++)
          acc[i][j] += av[i] * wv[j];
    }
  }
  float4 b0 = *(const float4*)(bias + 8 * tc);
  float4 b1 = *(const float4*)(bias + 8 * tc + 4);
  float bb[8] = {b0.x, b0.y, b0.z, b0.w, b1.x, b1.y, b1.z, b1.w};
  float4 o0 = *(const float4*)(ow + 8 * tc);
  float4 o1 = *(const float4*)(ow + 8 * tc + 4);
  float owv[8] = {o0.x, o0.y, o0.z, o0.w, o1.x, o1.y, o1.z, o1.w};
  float obv = obp[0];
  #pragma unroll
  for (int i = 0; i < 8; i++) {
    float v = 0.0f;
    #pragma unroll
    for (int j = 0; j < 8; j++)
      v += fmaxf(acc[i][j] + bb[j], 0.0f) * owv[j];
    v += __shfl_down(v, 4, 8);
    v += __shfl_down(v, 2, 8);
    v += __shfl_down(v, 1, 8);
    if (tc == 0) out[rowBase + 8 * tr + i] = v + obv;
  }
}

// ---------------- launch ----------------

extern "C" void kernel_launch(void* const* d_in, const int* in_sizes, int n_in,
                              void* d_out, int out_size, void* d_ws, size_t ws_size,
                              hipStream_t stream) {
  const float* X    = (const float*)d_in[0];
  const int*   EI   = (const int*)  d_in[1];
  const float* EW   = (const float*)d_in[2];
  const float* W1   = (const float*)d_in[3];
  const float* B1   = (const float*)d_in[4];
  const float* W2   = (const float*)d_in[5];
  const float* B2   = (const float*)d_in[6];
  const float* TC1W = (const float*)d_in[7];
  const float* TC1B = (const float*)d_in[8];
  const float* TC2W = (const float*)d_in[9];
  const float* TC2B = (const float*)d_in[10];
  const float* OW   = (const float*)d_in[11];
  const float* OB   = (const float*)d_in[12];
  float* out = (float*)d_out;

  char* base = (char*)d_ws;
  size_t off = 0;
  auto alloc = [&](size_t bytes) -> char* {
    char* p = base + off;
    off += (bytes + 255) & ~(size_t)255;
    return p;
  };
  float* deg   = (float*)alloc(N_NODES * 4);
  float* dinv  = (float*)alloc(N_NODES * 4);
  int*   cnt   = (int*)  alloc(N_NODES * 4);
  int*   rp    = (int*)  alloc((N_NODES + 1) * 4);
  int*   cur   = (int*)  alloc(N_NODES * 4);
  int*   csrc  = (int*)  alloc(EPAD * 4);
  float* cnorm = (float*)alloc(EPAD * 4);
  float* p1c   = (float*)alloc(192 * 128 * 4);
  float* p2c   = (float*)alloc(128 * 64 * 4);
  float* pb1   = (float*)alloc(128 * 4);
  const size_t BIG = (size_t)80000 * 192;
  float* h1buf = (float*)alloc(BIG * 4);   // h1; later t1 (80000x128)
  float* ahbuf = (float*)alloc(BIG * 4);   // ah; W2-GEMM in-place -> sp

  float* h1 = h1buf;
  float* ah = ahbuf;
  float* sp = ahbuf;
  float* t1 = h1buf;                        // 80000 x 128

  hipMemsetAsync(deg, 0, N_NODES * 4, stream);
  hipMemsetAsync(cnt, 0, N_NODES * 4, stream);
  k_deg_hist<<<625, 256, 0, stream>>>(EI, EW, deg, cnt);
  k_dinv<<<40, 256, 0, stream>>>(deg, dinv);
  k_scan<<<1, 1024, 0, stream>>>(cnt, rp, cur);
  k_fill<<<625, 256, 0, stream>>>(EI, EW, dinv, cur, csrc, cnorm);
  k_padfill<<<40, 256, 0, stream>>>(rp, cur, csrc, cnorm);
  k_pack<<<129, 256, 0, stream>>>(TC1W, TC2W, TC1B, p1c, p2c, pb1);

  // layer 1 (agg + W1 + relu), t=9..11 fused
  k_aggg1<<<20000, 256, 0, stream>>>(X, dinv, rp, csrc, cnorm, W1, B1, h1);
  // layer 2 aggregation, t3-sliced for L2 residency
  k_agg1t<<<60000, 256, 0, stream>>>(h1, dinv, rp, csrc, cnorm, ah);

  // sp = relu(ah @ W2 + b2): M=240000, K=64, N=64 (in-place)
  k_gemm<<<dim3(1875, 1), 128, 0, stream>>>(ah, 64, W2, 64, B2, sp, 64, 64);
  // t1 = relu(sp-rows @ p1c + pb1): M=80000, K=192, N=128 (both conv1 outputs)
  k_gemm<<<dim3(625, 2), 128, 0, stream>>>(sp, 192, p1c, 128, pb1, t1, 128, 192);
  // out = (relu(t1 @ p2c + tc2_b)) . ow + ob : fused conv2 + final
  k_gemm_out<<<625, 128, 0, stream>>>(t1, p2c, TC2B, OW, OB, out);
}